// Round 4
// baseline (2395.886 us; speedup 1.0000x reference)
//
#include <hip/hip_runtime.h>
#include <hip/hip_bf16.h>

// trackletGNN: 3x edge-conv + MLP head.
// R4: edge-centric aggregation. Edges are bucket-partitioned by dst (512
// nodes/bucket) with local node id packed in rec.x bits 21..29; each agg
// block owns one bucket, strides its ~4096 edges uniformly (no per-node
// segment walk -> no Poisson wave-tail divergence, which capped R3 at
// 3.65 TB/s gather with 5% VALU), and accumulates into LDS acc[512][9] f32
// via ds_add. k_csr + row_start deleted. Layer-1 gathers from a pre-cast
// bf16 x table (3 MB, L2-resident). Workspace ~171 MB (proven <=180).

#define NNODES 1500000
#define NEDGES 12000000
#define NTRACK 250000
#define HSTR   12          // bf16 feature stride (9 used) -> 24B records
#define NBUCK  2930        // ceil(NNODES/512)
#define CHUNK  16384       // edges per k_part/k_bhist block
#define PBLK   733         // ceil(NEDGES/CHUNK)
#define SRCMASK 0x1FFFFFu  // 21 bits

typedef unsigned int   u32;
typedef unsigned short u16;

static __device__ __forceinline__ float b2f(u32 v) {
    union { float f; u32 u; } x; x.u = v << 16; return x.f;
}
static __device__ __forceinline__ u16 f2b(float f) {
    __hip_bfloat16 h = __float2bfloat16(f);
    return *reinterpret_cast<u16*>(&h);
}
static __device__ __forceinline__ float ldw(const void* p, int i, int isf32) {
    return isf32 ? ((const float*)p)[i] : b2f((u32)((const u16*)p)[i]);
}

// ---------------- dtype probe ----------------

__global__ void k_detect(const u16* a, const u16* b, const u16* c,
                         const u16* d, const u16* e, const u16* f,
                         int* flag) {
    if (blockIdx.x == 0 && threadIdx.x == 0) {
        int isf32 = 0;
        const u16* ps[6] = {a, b, c, d, e, f};
        const int  ns[6] = {9, 9, 9, 9, 9, 8};
        for (int k = 0; k < 6; k++)
            for (int i = 0; i < ns[k]; i++) {
                float v = b2f((u32)ps[k][i]);
                if (!(fabsf(v) < 1.0e3f)) isf32 = 1;   // catches NaN/Inf too
            }
        *flag = isf32;
    }
}

// ---------------- x -> bf16 table (3 MB, L2-resident for layer 1) --------

__global__ __launch_bounds__(256) void k_xcast(const void* __restrict__ x,
                                               u16* __restrict__ xb,
                                               const int* __restrict__ flag) {
    int isf32 = *flag;
    int n = blockIdx.x * 256 + threadIdx.x;
    if (n < NNODES)
        xb[n] = isf32 ? f2b(((const float*)x)[n]) : ((const u16*)x)[n];
}

// ---------------- bucket histogram + scan ----------------

__global__ __launch_bounds__(256) void k_bhist(const int* __restrict__ dst,
                                               int* __restrict__ gh) {
    __shared__ u32 h[NBUCK];
    int t = threadIdx.x;
    for (int b = t; b < NBUCK; b += 256) h[b] = 0;
    __syncthreads();
    int c0 = blockIdx.x * CHUNK;
#pragma unroll 4
    for (int i = 0; i < CHUNK / 256; i++) {
        int e = c0 + i * 256 + t;
        if (e < NEDGES) atomicAdd(&h[((u32)dst[e]) >> 9], 1u);
    }
    __syncthreads();
    for (int b = t; b < NBUCK; b += 256) {
        u32 c = h[b];
        if (c) atomicAdd((u32*)&gh[b], c);
    }
}

__global__ __launch_bounds__(256) void k_bscan(const int* __restrict__ gh,
                                               int* __restrict__ bstart,
                                               int* __restrict__ gcur) {
    __shared__ u32 sd[256];
    __shared__ u32 carry;
    int t = threadIdx.x;
    if (t == 0) carry = 0;
    __syncthreads();
    for (int c0 = 0; c0 < NBUCK; c0 += 256) {
        int b = c0 + t;
        u32 v = (b < NBUCK) ? (u32)gh[b] : 0;
        sd[t] = v; __syncthreads();
        for (int o = 1; o < 256; o <<= 1) {
            u32 a = (t >= o) ? sd[t - o] : 0;
            __syncthreads();
            sd[t] += a;
            __syncthreads();
        }
        u32 excl = carry + sd[t] - v;
        if (b < NBUCK) { bstart[b] = (int)excl; gcur[b] = (int)excl; }
        __syncthreads();
        if (t == 255) carry += sd[255];
        __syncthreads();
    }
    if (t == 0) bstart[NBUCK] = NEDGES;
}

// ---------------- partition into buckets (run-reserved writes) ----------

__global__ __launch_bounds__(256) void k_part(const int* __restrict__ src,
                                              const int* __restrict__ dst,
                                              const void* __restrict__ attr,
                                              int* __restrict__ gcur,
                                              uint2* __restrict__ perm,
                                              const int* __restrict__ flag) {
    __shared__ u32 h[NBUCK];
    __shared__ u32 base[NBUCK];
    int isf32 = *flag;
    int t = threadIdx.x;
    for (int b = t; b < NBUCK; b += 256) h[b] = 0;
    __syncthreads();
    int c0 = blockIdx.x * CHUNK;
#pragma unroll 4
    for (int i = 0; i < CHUNK / 256; i++) {
        int e = c0 + i * 256 + t;
        if (e < NEDGES) atomicAdd(&h[((u32)dst[e]) >> 9], 1u);
    }
    __syncthreads();
    for (int b = t; b < NBUCK; b += 256) {
        u32 c = h[b];
        base[b] = c ? (u32)atomicAdd(&gcur[b], (int)c) : 0u;
        h[b] = 0;  // reuse as local cursor
    }
    __syncthreads();
#pragma unroll 4
    for (int i = 0; i < CHUNK / 256; i++) {
        int e = c0 + i * 256 + t;
        if (e < NEDGES) {
            u32 d  = (u32)dst[e];
            u32 bk = d >> 9;
            u32 off = atomicAdd(&h[bk], 1u);
            u32 pos = base[bk] + off;
            u32 ap;
            if (isf32) {
                float2 a = ((const float2*)attr)[e];
                ap = (u32)f2b(a.x) | ((u32)f2b(a.y) << 16);
            } else {
                ap = ((const u32*)attr)[e];
            }
            uint2 rec;
            rec.x = ((u32)src[e]) | ((d & 511u) << 21);
            rec.y = ap;
            perm[pos] = rec;
        }
    }
}

// ---- layer 1 (edge-centric): gather bf16 x, fuse Wx1+edge+Wo1+ReLU+Wx2 ----

__global__ __launch_bounds__(256) void k_eagg1(
        const int* __restrict__ bstart, const uint2* __restrict__ perm,
        const u16* __restrict__ xb,
        const void* Wx, const void* bx, const void* We, const void* be,
        const void* Wo, const void* bo, const void* Wxn, const void* bxn,
        u16* __restrict__ hout, const int* __restrict__ flag) {
    __shared__ float acc[512 * 9];
    __shared__ float sWx[9], sbx[9], sWe[18], sbe[9], sWo[81], sbo[9], sWxn[81], sbxn[9];
    int isf32 = *flag;
    int t = threadIdx.x;
    if (t < 9)  sWx[t]  = ldw(Wx,  t, isf32);
    if (t < 9)  sbx[t]  = ldw(bx,  t, isf32);
    if (t < 18) sWe[t]  = ldw(We,  t, isf32);
    if (t < 9)  sbe[t]  = ldw(be,  t, isf32);
    if (t < 81) sWo[t]  = ldw(Wo,  t, isf32);
    if (t < 9)  sbo[t]  = ldw(bo,  t, isf32);
    if (t < 81) sWxn[t] = ldw(Wxn, t, isf32);
    if (t < 9)  sbxn[t] = ldw(bxn, t, isf32);
    for (int i = t; i < 512 * 9; i += 256) acc[i] = 0.f;
    __syncthreads();

    int b = blockIdx.x;
    int r0 = bstart[b], r1 = bstart[b + 1];
    for (int i = r0 + t; i < r1; i += 256) {
        uint2 rec = perm[i];
        int   l   = (int)((rec.x >> 21) & 511u);
        float xs  = b2f((u32)xb[rec.x & SRCMASK]);
        float a0  = b2f(rec.y & 0xffffu);
        float a1  = b2f(rec.y >> 16);
        float* ap = &acc[l * 9];
#pragma unroll
        for (int j = 0; j < 9; j++) {
            float e  = fmaf(a0, sWe[2 * j], fmaf(a1, sWe[2 * j + 1], sbe[j]));
            float hh = fmaf(xs, sWx[j], sbx[j]);
            atomicAdd(&ap[j], hh * e);
        }
    }
    __syncthreads();

    for (int l = t; l < 512; l += 256) {
        int n = b * 512 + l;
        if (n >= NNODES) break;
        float o[9];
#pragma unroll
        for (int k = 0; k < 9; k++) {
            float v = sbo[k];
#pragma unroll
            for (int j = 0; j < 9; j++) v = fmaf(acc[l * 9 + j], sWo[k * 9 + j], v);
            o[k] = fmaxf(v, 0.f);
        }
        u16 hv[9];
#pragma unroll
        for (int j = 0; j < 9; j++) {
            float v = sbxn[j];
#pragma unroll
            for (int k = 0; k < 9; k++) v = fmaf(o[k], sWxn[j * 9 + k], v);
            hv[j] = f2b(v);
        }
        uint2* op = (uint2*)(hout + (size_t)n * HSTR);
        uint2 q;
        q.x = (u32)hv[0] | ((u32)hv[1] << 16); q.y = (u32)hv[2] | ((u32)hv[3] << 16); op[0] = q;
        q.x = (u32)hv[4] | ((u32)hv[5] << 16); q.y = (u32)hv[6] | ((u32)hv[7] << 16); op[1] = q;
        q.x = (u32)hv[8];                      q.y = 0;                               op[2] = q;
    }
}

// ---- layers 2/3 (edge-centric): gather 9-vec bf16 ----

template <int OUTF, bool FUSE_NEXT>
__global__ __launch_bounds__(256) void k_eagg(
        const int* __restrict__ bstart, const uint2* __restrict__ perm,
        const u16* __restrict__ hcur,
        const void* We, const void* be, const void* Wo, const void* bo,
        const void* Wxn, const void* bxn,
        u16* __restrict__ hout, const int* __restrict__ flag) {
    __shared__ float acc[512 * 9];
    __shared__ float sWe[18], sbe[9], sWo[OUTF * 9], sbo[OUTF], sWxn[81], sbxn[9];
    int isf32 = *flag;
    int t = threadIdx.x;
    if (t < 18)       sWe[t] = ldw(We, t, isf32);
    if (t < 9)        sbe[t] = ldw(be, t, isf32);
    if (t < OUTF * 9) sWo[t] = ldw(Wo, t, isf32);
    if (t < OUTF)     sbo[t] = ldw(bo, t, isf32);
    if constexpr (FUSE_NEXT) {
        if (t < 81) sWxn[t] = ldw(Wxn, t, isf32);
        if (t < 9)  sbxn[t] = ldw(bxn, t, isf32);
    }
    for (int i = t; i < 512 * 9; i += 256) acc[i] = 0.f;
    __syncthreads();

    int b = blockIdx.x;
    int r0 = bstart[b], r1 = bstart[b + 1];
    for (int i = r0 + t; i < r1; i += 256) {
        uint2 rec = perm[i];
        int   s   = (int)(rec.x & SRCMASK);
        int   l   = (int)((rec.x >> 21) & 511u);
        float a0  = b2f(rec.y & 0xffffu);
        float a1  = b2f(rec.y >> 16);
        const uint2* hp = (const uint2*)(hcur + (size_t)s * HSTR);
        uint2 q0 = hp[0], q1 = hp[1], q2 = hp[2];
        float h[9];
        h[0] = b2f(q0.x & 0xffffu); h[1] = b2f(q0.x >> 16);
        h[2] = b2f(q0.y & 0xffffu); h[3] = b2f(q0.y >> 16);
        h[4] = b2f(q1.x & 0xffffu); h[5] = b2f(q1.x >> 16);
        h[6] = b2f(q1.y & 0xffffu); h[7] = b2f(q1.y >> 16);
        h[8] = b2f(q2.x & 0xffffu);
        float* ap = &acc[l * 9];
#pragma unroll
        for (int j = 0; j < 9; j++) {
            float e = fmaf(a0, sWe[2 * j], fmaf(a1, sWe[2 * j + 1], sbe[j]));
            atomicAdd(&ap[j], h[j] * e);
        }
    }
    __syncthreads();

    for (int l = t; l < 512; l += 256) {
        int n = b * 512 + l;
        if (n >= NNODES) break;
        float o[OUTF];
#pragma unroll
        for (int k = 0; k < OUTF; k++) {
            float v = sbo[k];
#pragma unroll
            for (int j = 0; j < 9; j++) v = fmaf(acc[l * 9 + j], sWo[k * 9 + j], v);
            o[k] = fmaxf(v, 0.f);
        }
        if constexpr (FUSE_NEXT) {
            u16 hv[9];
#pragma unroll
            for (int j = 0; j < 9; j++) {
                float v = sbxn[j];
#pragma unroll
                for (int k = 0; k < OUTF; k++) v = fmaf(o[k], sWxn[j * 9 + k], v);
                hv[j] = f2b(v);
            }
            uint2* op = (uint2*)(hout + (size_t)n * HSTR);
            uint2 q;
            q.x = (u32)hv[0] | ((u32)hv[1] << 16); q.y = (u32)hv[2] | ((u32)hv[3] << 16); op[0] = q;
            q.x = (u32)hv[4] | ((u32)hv[5] << 16); q.y = (u32)hv[6] | ((u32)hv[7] << 16); op[1] = q;
            q.x = (u32)hv[8];                      q.y = 0;                               op[2] = q;
        } else {
            uint2 q;
            q.x = (u32)f2b(o[0]) | ((u32)f2b(o[1]) << 16);
            q.y = (u32)f2b(o[2]) | ((u32)f2b(o[3]) << 16);
            ((uint2*)(hout + (size_t)n * 4))[0] = q;
        }
    }
}

// ---------------- head MLP + log_softmax ----------------

__global__ __launch_bounds__(256) void k_head(
        const u16* __restrict__ f,
        const void* W1, const void* b1, const void* W2, const void* b2,
        void* __restrict__ out, const int* __restrict__ flag) {
    __shared__ float sW1[192], sb1[8], sW2[32], sb2[4];
    int isf32 = *flag;
    int t = threadIdx.x;
    if (t < 192) sW1[t] = ldw(W1, t, isf32);
    if (t < 8)   sb1[t] = ldw(b1, t, isf32);
    if (t < 32)  sW2[t] = ldw(W2, t, isf32);
    if (t < 4)   sb2[t] = ldw(b2, t, isf32);
    __syncthreads();

    int tr = blockIdx.x * 256 + t;
    if (tr >= NTRACK) return;

    const uint4* fp = (const uint4*)(f + (size_t)tr * 24);
    uint4 A = fp[0], B = fp[1], C = fp[2];
    u32 w[12] = {A.x, A.y, A.z, A.w, B.x, B.y, B.z, B.w, C.x, C.y, C.z, C.w};
    float in[24];
#pragma unroll
    for (int i = 0; i < 12; i++) {
        in[2 * i]     = b2f(w[i] & 0xffffu);
        in[2 * i + 1] = b2f(w[i] >> 16);
    }

    float z1[8];
#pragma unroll
    for (int o = 0; o < 8; o++) {
        float v = sb1[o];
#pragma unroll
        for (int i = 0; i < 24; i++) v = fmaf(in[i], sW1[o * 24 + i], v);
        z1[o] = fmaxf(v, 0.f);
    }
    float z2[4];
#pragma unroll
    for (int c = 0; c < 4; c++) {
        float v = sb2[c];
#pragma unroll
        for (int o = 0; o < 8; o++) v = fmaf(z1[o], sW2[c * 8 + o], v);
        z2[c] = v;
    }
    float m = fmaxf(fmaxf(z2[0], z2[1]), fmaxf(z2[2], z2[3]));
    float s = 0.f;
#pragma unroll
    for (int c = 0; c < 4; c++) s += expf(z2[c] - m);
    float l = logf(s) + m;

    if (isf32) {
        float4 q; q.x = z2[0] - l; q.y = z2[1] - l; q.z = z2[2] - l; q.w = z2[3] - l;
        ((float4*)((float*)out + (size_t)tr * 4))[0] = q;
    } else {
        uint2 q;
        q.x = (u32)f2b(z2[0] - l) | ((u32)f2b(z2[1] - l) << 16);
        q.y = (u32)f2b(z2[2] - l) | ((u32)f2b(z2[3] - l) << 16);
        ((uint2*)((u16*)out + (size_t)tr * 4))[0] = q;
    }
}

// ---------------- host ----------------

extern "C" void kernel_launch(void* const* d_in, const int* in_sizes, int n_in,
                              void* d_out, int out_size, void* d_ws, size_t ws_size,
                              hipStream_t stream) {
    const void* X    = d_in[0];
    const int* eidx  = (const int*)d_in[1];
    const void* eattr= d_in[2];
    const void *WX1 = d_in[3],  *BX1 = d_in[4];
    const void *WE1 = d_in[5],  *BE1 = d_in[6];
    const void *WO1 = d_in[7],  *BO1 = d_in[8];
    const void *WX2 = d_in[9],  *BX2 = d_in[10];
    const void *WE2 = d_in[11], *BE2 = d_in[12];
    const void *WO2 = d_in[13], *BO2 = d_in[14];
    const void *WX3 = d_in[15], *BX3 = d_in[16];
    const void *WE3 = d_in[17], *BE3 = d_in[18];
    const void *WO3 = d_in[19], *BO3 = d_in[20];
    const void *W1  = d_in[21], *B1  = d_in[22];
    const void *W2  = d_in[23], *B2  = d_in[24];

    const int* src = eidx;
    const int* dst = eidx + NEDGES;

    // workspace layout (~171 MB)
    char* w = (char*)d_ws;
    size_t off = 0;
    auto take = [&](size_t bytes) -> void* {
        void* p = w + off;
        off += (bytes + 255) & ~(size_t)255;
        return p;
    };
    int*   flag      = (int*)take(256);
    int*   gh        = (int*)take((size_t)NBUCK * 4);
    int*   bstart    = (int*)take((size_t)(NBUCK + 1) * 4);
    int*   gcur      = (int*)take((size_t)NBUCK * 4);
    u16*   xb        = (u16*)take((size_t)NNODES * 2);         // 3 MB bf16 x
    uint2* perm      = (uint2*)take((size_t)NEDGES * 8);       // 96 MB
    u16*   h2        = (u16*)take((size_t)NNODES * HSTR * 2);  // 36 MB
    u16*   h3        = (u16*)take((size_t)NNODES * HSTR * 2);  // 36 MB
    u16*   f         = h2;  // layer-3 output (12 MB) reuses h2 (dead by then)
    (void)ws_size; (void)n_in; (void)in_sizes; (void)out_size;

    const int NB = (NNODES + 255) / 256;
    const int TB = (NTRACK + 255) / 256;

    hipMemsetAsync(gh, 0, (size_t)NBUCK * 4, stream);

    k_detect <<<1,     64,  0, stream>>>((const u16*)BX1, (const u16*)BE1, (const u16*)BO1,
                                         (const u16*)BX2, (const u16*)BE2, (const u16*)B1, flag);
    k_xcast  <<<NB,    256, 0, stream>>>(X, xb, flag);
    k_bhist  <<<PBLK,  256, 0, stream>>>(dst, gh);
    k_bscan  <<<1,     256, 0, stream>>>(gh, bstart, gcur);
    k_part   <<<PBLK,  256, 0, stream>>>(src, dst, eattr, gcur, perm, flag);

    k_eagg1        <<<NBUCK, 256, 0, stream>>>(bstart, perm, xb,
                                               WX1, BX1, WE1, BE1, WO1, BO1, WX2, BX2, h2, flag);
    k_eagg<9,true> <<<NBUCK, 256, 0, stream>>>(bstart, perm, h2,
                                               WE2, BE2, WO2, BO2, WX3, BX3, h3, flag);
    k_eagg<4,false><<<NBUCK, 256, 0, stream>>>(bstart, perm, h3,
                                               WE3, BE3, WO3, BO3, WO3, BO3, f, flag);
    k_head         <<<TB,    256, 0, stream>>>(f, W1, B1, W2, B2, d_out, flag);
}

// Round 5
// 1344.787 us; speedup vs baseline: 1.7816x; 1.7816x over previous
//
#include <hip/hip_runtime.h>
#include <hip/hip_bf16.h>

// trackletGNN: 3x edge-conv + MLP head.
// R5: edge-centric aggregation kept (uniform edge striding, no Poisson-tail
// divergence), but the R4 killer is fixed: atomicAdd on __shared__ FLOAT
// compiled to a CAS loop (~2 dependent LDS round-trips x 9 per edge ->
// thousands of cycles/edge; counters showed VALU 3.8%, FETCH 71MB, conflicts
// 0 => pure serialization). Accumulators are now FIXED-POINT int32 (scale
// 2^24) using native fire-and-forget ds_add_u32. Gather table split into
// 16B-aligned h[0..7] (never straddles a cache line) + 2B h[8] (L2-resident)
// to kill the 25% line-straddle amplification of 24B records.
// Workspace ~153 MB.

#define NNODES 1500000
#define NEDGES 12000000
#define NTRACK 250000
#define NBUCK  2930        // ceil(NNODES/512)
#define CHUNK  16384       // edges per k_part/k_bhist block
#define PBLK   733         // ceil(NEDGES/CHUNK)
#define SRCMASK 0x1FFFFFu  // 21 bits
#define FXSCALE 16777216.f // 2^24
#define FXINV   (1.f / 16777216.f)

typedef unsigned int   u32;
typedef unsigned short u16;

static __device__ __forceinline__ float b2f(u32 v) {
    union { float f; u32 u; } x; x.u = v << 16; return x.f;
}
static __device__ __forceinline__ u16 f2b(float f) {
    __hip_bfloat16 h = __float2bfloat16(f);
    return *reinterpret_cast<u16*>(&h);
}
static __device__ __forceinline__ float ldw(const void* p, int i, int isf32) {
    return isf32 ? ((const float*)p)[i] : b2f((u32)((const u16*)p)[i]);
}
static __device__ __forceinline__ int fx(float f) {
    return (int)rintf(f * FXSCALE);
}

// ---------------- dtype probe ----------------

__global__ void k_detect(const u16* a, const u16* b, const u16* c,
                         const u16* d, const u16* e, const u16* f,
                         int* flag) {
    if (blockIdx.x == 0 && threadIdx.x == 0) {
        int isf32 = 0;
        const u16* ps[6] = {a, b, c, d, e, f};
        const int  ns[6] = {9, 9, 9, 9, 9, 8};
        for (int k = 0; k < 6; k++)
            for (int i = 0; i < ns[k]; i++) {
                float v = b2f((u32)ps[k][i]);
                if (!(fabsf(v) < 1.0e3f)) isf32 = 1;   // catches NaN/Inf too
            }
        *flag = isf32;
    }
}

// ---------------- x -> bf16 table (3 MB, L2-resident for layer 1) --------

__global__ __launch_bounds__(256) void k_xcast(const void* __restrict__ x,
                                               u16* __restrict__ xb,
                                               const int* __restrict__ flag) {
    int isf32 = *flag;
    int n = blockIdx.x * 256 + threadIdx.x;
    if (n < NNODES)
        xb[n] = isf32 ? f2b(((const float*)x)[n]) : ((const u16*)x)[n];
}

// ---------------- bucket histogram + scan ----------------

__global__ __launch_bounds__(256) void k_bhist(const int* __restrict__ dst,
                                               int* __restrict__ gh) {
    __shared__ u32 h[NBUCK];
    int t = threadIdx.x;
    for (int b = t; b < NBUCK; b += 256) h[b] = 0;
    __syncthreads();
    int c0 = blockIdx.x * CHUNK;
#pragma unroll 4
    for (int i = 0; i < CHUNK / 256; i++) {
        int e = c0 + i * 256 + t;
        if (e < NEDGES) atomicAdd(&h[((u32)dst[e]) >> 9], 1u);
    }
    __syncthreads();
    for (int b = t; b < NBUCK; b += 256) {
        u32 c = h[b];
        if (c) atomicAdd((u32*)&gh[b], c);
    }
}

__global__ __launch_bounds__(256) void k_bscan(const int* __restrict__ gh,
                                               int* __restrict__ bstart,
                                               int* __restrict__ gcur) {
    __shared__ u32 sd[256];
    __shared__ u32 carry;
    int t = threadIdx.x;
    if (t == 0) carry = 0;
    __syncthreads();
    for (int c0 = 0; c0 < NBUCK; c0 += 256) {
        int b = c0 + t;
        u32 v = (b < NBUCK) ? (u32)gh[b] : 0;
        sd[t] = v; __syncthreads();
        for (int o = 1; o < 256; o <<= 1) {
            u32 a = (t >= o) ? sd[t - o] : 0;
            __syncthreads();
            sd[t] += a;
            __syncthreads();
        }
        u32 excl = carry + sd[t] - v;
        if (b < NBUCK) { bstart[b] = (int)excl; gcur[b] = (int)excl; }
        __syncthreads();
        if (t == 255) carry += sd[255];
        __syncthreads();
    }
    if (t == 0) bstart[NBUCK] = NEDGES;
}

// ---------------- partition into buckets (run-reserved writes) ----------

__global__ __launch_bounds__(256) void k_part(const int* __restrict__ src,
                                              const int* __restrict__ dst,
                                              const void* __restrict__ attr,
                                              int* __restrict__ gcur,
                                              uint2* __restrict__ perm,
                                              const int* __restrict__ flag) {
    __shared__ u32 h[NBUCK];
    __shared__ u32 base[NBUCK];
    int isf32 = *flag;
    int t = threadIdx.x;
    for (int b = t; b < NBUCK; b += 256) h[b] = 0;
    __syncthreads();
    int c0 = blockIdx.x * CHUNK;
#pragma unroll 4
    for (int i = 0; i < CHUNK / 256; i++) {
        int e = c0 + i * 256 + t;
        if (e < NEDGES) atomicAdd(&h[((u32)dst[e]) >> 9], 1u);
    }
    __syncthreads();
    for (int b = t; b < NBUCK; b += 256) {
        u32 c = h[b];
        base[b] = c ? (u32)atomicAdd(&gcur[b], (int)c) : 0u;
        h[b] = 0;  // reuse as local cursor
    }
    __syncthreads();
#pragma unroll 4
    for (int i = 0; i < CHUNK / 256; i++) {
        int e = c0 + i * 256 + t;
        if (e < NEDGES) {
            u32 d  = (u32)dst[e];
            u32 bk = d >> 9;
            u32 off = atomicAdd(&h[bk], 1u);
            u32 pos = base[bk] + off;
            u32 ap;
            if (isf32) {
                float2 a = ((const float2*)attr)[e];
                ap = (u32)f2b(a.x) | ((u32)f2b(a.y) << 16);
            } else {
                ap = ((const u32*)attr)[e];
            }
            uint2 rec;
            rec.x = ((u32)src[e]) | ((d & 511u) << 21);
            rec.y = ap;
            perm[pos] = rec;
        }
    }
}

// ---- layer 1 (edge-centric): gather bf16 x, fixed-point LDS accumulate ----

__global__ __launch_bounds__(256) void k_eagg1(
        const int* __restrict__ bstart, const uint2* __restrict__ perm,
        const u16* __restrict__ xb,
        const void* Wx, const void* bx, const void* We, const void* be,
        const void* Wo, const void* bo, const void* Wxn, const void* bxn,
        uint4* __restrict__ hA, u16* __restrict__ hB,
        const int* __restrict__ flag) {
    __shared__ int acc[512 * 9];
    __shared__ float sWx[9], sbx[9], sWe[18], sbe[9], sWo[81], sbo[9], sWxn[81], sbxn[9];
    int isf32 = *flag;
    int t = threadIdx.x;
    if (t < 9)  sWx[t]  = ldw(Wx,  t, isf32);
    if (t < 9)  sbx[t]  = ldw(bx,  t, isf32);
    if (t < 18) sWe[t]  = ldw(We,  t, isf32);
    if (t < 9)  sbe[t]  = ldw(be,  t, isf32);
    if (t < 81) sWo[t]  = ldw(Wo,  t, isf32);
    if (t < 9)  sbo[t]  = ldw(bo,  t, isf32);
    if (t < 81) sWxn[t] = ldw(Wxn, t, isf32);
    if (t < 9)  sbxn[t] = ldw(bxn, t, isf32);
    for (int i = t; i < 512 * 9; i += 256) acc[i] = 0;
    __syncthreads();

    int b = blockIdx.x;
    int r0 = bstart[b], r1 = bstart[b + 1];
    for (int i = r0 + t; i < r1; i += 256) {
        uint2 rec = perm[i];
        int   l   = (int)((rec.x >> 21) & 511u);
        float xs  = b2f((u32)xb[rec.x & SRCMASK]);
        float a0  = b2f(rec.y & 0xffffu);
        float a1  = b2f(rec.y >> 16);
        int* ap = &acc[l * 9];
#pragma unroll
        for (int j = 0; j < 9; j++) {
            float e  = fmaf(a0, sWe[2 * j], fmaf(a1, sWe[2 * j + 1], sbe[j]));
            float hh = fmaf(xs, sWx[j], sbx[j]);
            atomicAdd(&ap[j], fx(hh * e));   // native ds_add_u32, fire-and-forget
        }
    }
    __syncthreads();

    for (int l = t; l < 512; l += 256) {
        int n = b * 512 + l;
        if (n >= NNODES) break;
        float av[9];
#pragma unroll
        for (int j = 0; j < 9; j++) av[j] = (float)acc[l * 9 + j] * FXINV;
        float o[9];
#pragma unroll
        for (int k = 0; k < 9; k++) {
            float v = sbo[k];
#pragma unroll
            for (int j = 0; j < 9; j++) v = fmaf(av[j], sWo[k * 9 + j], v);
            o[k] = fmaxf(v, 0.f);
        }
        u16 hv[9];
#pragma unroll
        for (int j = 0; j < 9; j++) {
            float v = sbxn[j];
#pragma unroll
            for (int k = 0; k < 9; k++) v = fmaf(o[k], sWxn[j * 9 + k], v);
            hv[j] = f2b(v);
        }
        uint4 q;
        q.x = (u32)hv[0] | ((u32)hv[1] << 16);
        q.y = (u32)hv[2] | ((u32)hv[3] << 16);
        q.z = (u32)hv[4] | ((u32)hv[5] << 16);
        q.w = (u32)hv[6] | ((u32)hv[7] << 16);
        hA[n] = q;
        hB[n] = hv[8];
    }
}

// ---- layers 2/3 (edge-centric): gather 16B+2B, fixed-point LDS accumulate --

template <int OUTF, bool FUSE_NEXT>
__global__ __launch_bounds__(256) void k_eagg(
        const int* __restrict__ bstart, const uint2* __restrict__ perm,
        const uint4* __restrict__ hA, const u16* __restrict__ hB,
        const void* We, const void* be, const void* Wo, const void* bo,
        const void* Wxn, const void* bxn,
        uint4* __restrict__ oA, u16* __restrict__ oB,
        const int* __restrict__ flag) {
    __shared__ int acc[512 * 9];
    __shared__ float sWe[18], sbe[9], sWo[OUTF * 9], sbo[OUTF], sWxn[81], sbxn[9];
    int isf32 = *flag;
    int t = threadIdx.x;
    if (t < 18)       sWe[t] = ldw(We, t, isf32);
    if (t < 9)        sbe[t] = ldw(be, t, isf32);
    if (t < OUTF * 9) sWo[t] = ldw(Wo, t, isf32);
    if (t < OUTF)     sbo[t] = ldw(bo, t, isf32);
    if constexpr (FUSE_NEXT) {
        if (t < 81) sWxn[t] = ldw(Wxn, t, isf32);
        if (t < 9)  sbxn[t] = ldw(bxn, t, isf32);
    }
    for (int i = t; i < 512 * 9; i += 256) acc[i] = 0;
    __syncthreads();

    int b = blockIdx.x;
    int r0 = bstart[b], r1 = bstart[b + 1];
    for (int i = r0 + t; i < r1; i += 256) {
        uint2 rec = perm[i];
        int   s   = (int)(rec.x & SRCMASK);
        int   l   = (int)((rec.x >> 21) & 511u);
        float a0  = b2f(rec.y & 0xffffu);
        float a1  = b2f(rec.y >> 16);
        uint4 qa  = hA[s];
        u32   qb  = (u32)hB[s];
        float h[9];
        h[0] = b2f(qa.x & 0xffffu); h[1] = b2f(qa.x >> 16);
        h[2] = b2f(qa.y & 0xffffu); h[3] = b2f(qa.y >> 16);
        h[4] = b2f(qa.z & 0xffffu); h[5] = b2f(qa.z >> 16);
        h[6] = b2f(qa.w & 0xffffu); h[7] = b2f(qa.w >> 16);
        h[8] = b2f(qb);
        int* ap = &acc[l * 9];
#pragma unroll
        for (int j = 0; j < 9; j++) {
            float e = fmaf(a0, sWe[2 * j], fmaf(a1, sWe[2 * j + 1], sbe[j]));
            atomicAdd(&ap[j], fx(h[j] * e));
        }
    }
    __syncthreads();

    for (int l = t; l < 512; l += 256) {
        int n = b * 512 + l;
        if (n >= NNODES) break;
        float av[9];
#pragma unroll
        for (int j = 0; j < 9; j++) av[j] = (float)acc[l * 9 + j] * FXINV;
        float o[OUTF];
#pragma unroll
        for (int k = 0; k < OUTF; k++) {
            float v = sbo[k];
#pragma unroll
            for (int j = 0; j < 9; j++) v = fmaf(av[j], sWo[k * 9 + j], v);
            o[k] = fmaxf(v, 0.f);
        }
        if constexpr (FUSE_NEXT) {
            u16 hv[9];
#pragma unroll
            for (int j = 0; j < 9; j++) {
                float v = sbxn[j];
#pragma unroll
                for (int k = 0; k < OUTF; k++) v = fmaf(o[k], sWxn[j * 9 + k], v);
                hv[j] = f2b(v);
            }
            uint4 q;
            q.x = (u32)hv[0] | ((u32)hv[1] << 16);
            q.y = (u32)hv[2] | ((u32)hv[3] << 16);
            q.z = (u32)hv[4] | ((u32)hv[5] << 16);
            q.w = (u32)hv[6] | ((u32)hv[7] << 16);
            oA[n] = q;
            oB[n] = hv[8];
        } else {
            uint2 q;
            q.x = (u32)f2b(o[0]) | ((u32)f2b(o[1]) << 16);
            q.y = (u32)f2b(o[2]) | ((u32)f2b(o[3]) << 16);
            ((uint2*)oA)[n] = q;   // f table: 8B/node
        }
    }
}

// ---------------- head MLP + log_softmax ----------------

__global__ __launch_bounds__(256) void k_head(
        const u16* __restrict__ f,
        const void* W1, const void* b1, const void* W2, const void* b2,
        void* __restrict__ out, const int* __restrict__ flag) {
    __shared__ float sW1[192], sb1[8], sW2[32], sb2[4];
    int isf32 = *flag;
    int t = threadIdx.x;
    if (t < 192) sW1[t] = ldw(W1, t, isf32);
    if (t < 8)   sb1[t] = ldw(b1, t, isf32);
    if (t < 32)  sW2[t] = ldw(W2, t, isf32);
    if (t < 4)   sb2[t] = ldw(b2, t, isf32);
    __syncthreads();

    int tr = blockIdx.x * 256 + t;
    if (tr >= NTRACK) return;

    const uint4* fp = (const uint4*)(f + (size_t)tr * 24);
    uint4 A = fp[0], B = fp[1], C = fp[2];
    u32 w[12] = {A.x, A.y, A.z, A.w, B.x, B.y, B.z, B.w, C.x, C.y, C.z, C.w};
    float in[24];
#pragma unroll
    for (int i = 0; i < 12; i++) {
        in[2 * i]     = b2f(w[i] & 0xffffu);
        in[2 * i + 1] = b2f(w[i] >> 16);
    }

    float z1[8];
#pragma unroll
    for (int o = 0; o < 8; o++) {
        float v = sb1[o];
#pragma unroll
        for (int i = 0; i < 24; i++) v = fmaf(in[i], sW1[o * 24 + i], v);
        z1[o] = fmaxf(v, 0.f);
    }
    float z2[4];
#pragma unroll
    for (int c = 0; c < 4; c++) {
        float v = sb2[c];
#pragma unroll
        for (int o = 0; o < 8; o++) v = fmaf(z1[o], sW2[c * 8 + o], v);
        z2[c] = v;
    }
    float m = fmaxf(fmaxf(z2[0], z2[1]), fmaxf(z2[2], z2[3]));
    float s = 0.f;
#pragma unroll
    for (int c = 0; c < 4; c++) s += expf(z2[c] - m);
    float l = logf(s) + m;

    if (isf32) {
        float4 q; q.x = z2[0] - l; q.y = z2[1] - l; q.z = z2[2] - l; q.w = z2[3] - l;
        ((float4*)((float*)out + (size_t)tr * 4))[0] = q;
    } else {
        uint2 q;
        q.x = (u32)f2b(z2[0] - l) | ((u32)f2b(z2[1] - l) << 16);
        q.y = (u32)f2b(z2[2] - l) | ((u32)f2b(z2[3] - l) << 16);
        ((uint2*)((u16*)out + (size_t)tr * 4))[0] = q;
    }
}

// ---------------- host ----------------

extern "C" void kernel_launch(void* const* d_in, const int* in_sizes, int n_in,
                              void* d_out, int out_size, void* d_ws, size_t ws_size,
                              hipStream_t stream) {
    const void* X    = d_in[0];
    const int* eidx  = (const int*)d_in[1];
    const void* eattr= d_in[2];
    const void *WX1 = d_in[3],  *BX1 = d_in[4];
    const void *WE1 = d_in[5],  *BE1 = d_in[6];
    const void *WO1 = d_in[7],  *BO1 = d_in[8];
    const void *WX2 = d_in[9],  *BX2 = d_in[10];
    const void *WE2 = d_in[11], *BE2 = d_in[12];
    const void *WO2 = d_in[13], *BO2 = d_in[14];
    const void *WX3 = d_in[15], *BX3 = d_in[16];
    const void *WE3 = d_in[17], *BE3 = d_in[18];
    const void *WO3 = d_in[19], *BO3 = d_in[20];
    const void *W1  = d_in[21], *B1  = d_in[22];
    const void *W2  = d_in[23], *B2  = d_in[24];

    const int* src = eidx;
    const int* dst = eidx + NEDGES;

    // workspace layout (~153 MB)
    char* w = (char*)d_ws;
    size_t off = 0;
    auto take = [&](size_t bytes) -> void* {
        void* p = w + off;
        off += (bytes + 255) & ~(size_t)255;
        return p;
    };
    int*   flag   = (int*)take(256);
    int*   gh     = (int*)take((size_t)NBUCK * 4);
    int*   bstart = (int*)take((size_t)(NBUCK + 1) * 4);
    int*   gcur   = (int*)take((size_t)NBUCK * 4);
    u16*   xb     = (u16*)take((size_t)NNODES * 2);        // 3 MB
    uint2* perm   = (uint2*)take((size_t)NEDGES * 8);      // 96 MB
    uint4* hA2    = (uint4*)take((size_t)NNODES * 16);     // 24 MB
    u16*   hB2    = (u16*)take((size_t)NNODES * 2);        // 3 MB
    uint4* hA3    = (uint4*)take((size_t)NNODES * 16);     // 24 MB
    u16*   hB3    = (u16*)take((size_t)NNODES * 2);        // 3 MB
    u16*   f      = (u16*)hA2;  // layer-3 output (12 MB) reuses hA2 (dead by then)
    (void)ws_size; (void)n_in; (void)in_sizes; (void)out_size;

    const int NB = (NNODES + 255) / 256;
    const int TB = (NTRACK + 255) / 256;

    hipMemsetAsync(gh, 0, (size_t)NBUCK * 4, stream);

    k_detect <<<1,     64,  0, stream>>>((const u16*)BX1, (const u16*)BE1, (const u16*)BO1,
                                         (const u16*)BX2, (const u16*)BE2, (const u16*)B1, flag);
    k_xcast  <<<NB,    256, 0, stream>>>(X, xb, flag);
    k_bhist  <<<PBLK,  256, 0, stream>>>(dst, gh);
    k_bscan  <<<1,     256, 0, stream>>>(gh, bstart, gcur);
    k_part   <<<PBLK,  256, 0, stream>>>(src, dst, eattr, gcur, perm, flag);

    k_eagg1        <<<NBUCK, 256, 0, stream>>>(bstart, perm, xb,
                                               WX1, BX1, WE1, BE1, WO1, BO1, WX2, BX2,
                                               hA2, hB2, flag);
    k_eagg<9,true> <<<NBUCK, 256, 0, stream>>>(bstart, perm, hA2, hB2,
                                               WE2, BE2, WO2, BO2, WX3, BX3,
                                               hA3, hB3, flag);
    k_eagg<4,false><<<NBUCK, 256, 0, stream>>>(bstart, perm, hA3, hB3,
                                               WE3, BE3, WO3, BO3, WO3, BO3,
                                               (uint4*)f, (u16*)f, flag);
    k_head         <<<TB,    256, 0, stream>>>(f, W1, B1, W2, B2, d_out, flag);
}

// Round 6
// 1333.979 us; speedup vs baseline: 1.7960x; 1.0081x over previous
//
#include <hip/hip_runtime.h>
#include <hip/hip_bf16.h>

// trackletGNN: 3x edge-conv + MLP head.
// R6: partition write-amplification fix. R5's k_part wrote ~5.6-record (45B)
// runs scattered over 96MB -> 380MB HBM writes (4x) because run-boundary
// lines are shared across blocks/XCDs and evicted partial. Now buckets are
// 1024 nodes (NBUCK=1465), chunks 32768 edges, and every (block,bucket)
// reservation is ROUNDED UP to 8 records = 64B: all runs line-aligned and
// line-exclusive, tails filled with dummy records routed to an LDS trash
// accumulator row (l=1024) in the agg kernels. Expected writes ~=111MB, 1x.
// Aggs keep R5's fixed-point ds_add_u32 accumulation (CAS-free), now with
// 1024-node buckets (acc 36.9KB LDS, 4 blocks/CU). Workspace ~180.1MB
// (<= R2's proven 180.4MB); k_xcast dropped, layer1 gathers x directly.

#define NNODES 1500000
#define NEDGES 12000000
#define NTRACK 250000
#define NBUCK  1465        // ceil(NNODES/1024)
#define CHUNK  32768       // edges per k_part/k_bhist block
#define PBLK   367         // ceil(NEDGES/CHUNK)
#define PERMCAP (NEDGES + PBLK * NBUCK * 7)  // padded worst case: 15,763,585
#define SRCMASK 0x1FFFFFu  // 21 bits
#define TRASH   1024u      // dummy local-node id -> trash acc row
#define FXSCALE 16777216.f // 2^24
#define FXINV   (1.f / 16777216.f)

typedef unsigned int   u32;
typedef unsigned short u16;

static __device__ __forceinline__ float b2f(u32 v) {
    union { float f; u32 u; } x; x.u = v << 16; return x.f;
}
static __device__ __forceinline__ u16 f2b(float f) {
    __hip_bfloat16 h = __float2bfloat16(f);
    return *reinterpret_cast<u16*>(&h);
}
static __device__ __forceinline__ float ldw(const void* p, int i, int isf32) {
    return isf32 ? ((const float*)p)[i] : b2f((u32)((const u16*)p)[i]);
}
static __device__ __forceinline__ int fx(float f) {
    return (int)rintf(f * FXSCALE);
}
static __device__ __forceinline__ u32 rup8(u32 c) { return (c + 7u) & ~7u; }

// ---------------- dtype probe ----------------

__global__ void k_detect(const u16* a, const u16* b, const u16* c,
                         const u16* d, const u16* e, const u16* f,
                         int* flag) {
    if (blockIdx.x == 0 && threadIdx.x == 0) {
        int isf32 = 0;
        const u16* ps[6] = {a, b, c, d, e, f};
        const int  ns[6] = {9, 9, 9, 9, 9, 8};
        for (int k = 0; k < 6; k++)
            for (int i = 0; i < ns[k]; i++) {
                float v = b2f((u32)ps[k][i]);
                if (!(fabsf(v) < 1.0e3f)) isf32 = 1;   // catches NaN/Inf too
            }
        *flag = isf32;
    }
}

// ---------------- bucket histogram (padded counts) + scan ----------------

__global__ __launch_bounds__(512) void k_bhist(const int* __restrict__ dst,
                                               int* __restrict__ gh) {
    __shared__ u32 h[NBUCK];
    int t = threadIdx.x;
    for (int b = t; b < NBUCK; b += 512) h[b] = 0;
    __syncthreads();
    int c0 = blockIdx.x * CHUNK;
#pragma unroll 4
    for (int i = 0; i < CHUNK / 512; i++) {
        int e = c0 + i * 512 + t;
        if (e < NEDGES) atomicAdd(&h[((u32)dst[e]) >> 10], 1u);
    }
    __syncthreads();
    for (int b = t; b < NBUCK; b += 512) {
        u32 c = rup8(h[b]);
        if (c) atomicAdd((u32*)&gh[b], c);
    }
}

__global__ __launch_bounds__(256) void k_bscan(const int* __restrict__ gh,
                                               int* __restrict__ bstart,
                                               int* __restrict__ gcur) {
    __shared__ u32 sd[256];
    __shared__ u32 carry;
    int t = threadIdx.x;
    if (t == 0) carry = 0;
    __syncthreads();
    for (int c0 = 0; c0 < NBUCK; c0 += 256) {
        int b = c0 + t;
        u32 v = (b < NBUCK) ? (u32)gh[b] : 0;
        sd[t] = v; __syncthreads();
        for (int o = 1; o < 256; o <<= 1) {
            u32 a = (t >= o) ? sd[t - o] : 0;
            __syncthreads();
            sd[t] += a;
            __syncthreads();
        }
        u32 excl = carry + sd[t] - v;
        if (b < NBUCK) { bstart[b] = (int)excl; gcur[b] = (int)excl; }
        __syncthreads();
        if (t == 255) carry += sd[255];
        __syncthreads();
    }
    if (t == 0) bstart[NBUCK] = (int)carry;   // padded total
}

// ------- partition into buckets: 64B-aligned padded run reservations -------

__global__ __launch_bounds__(512) void k_part(const int* __restrict__ src,
                                              const int* __restrict__ dst,
                                              const void* __restrict__ attr,
                                              int* __restrict__ gcur,
                                              uint2* __restrict__ perm,
                                              const int* __restrict__ flag) {
    __shared__ u32 h[NBUCK];
    __shared__ u32 base[NBUCK];
    int isf32 = *flag;
    int t = threadIdx.x;
    for (int b = t; b < NBUCK; b += 512) h[b] = 0;
    __syncthreads();
    int c0 = blockIdx.x * CHUNK;
#pragma unroll 4
    for (int i = 0; i < CHUNK / 512; i++) {
        int e = c0 + i * 512 + t;
        if (e < NEDGES) atomicAdd(&h[((u32)dst[e]) >> 10], 1u);
    }
    __syncthreads();
    for (int b = t; b < NBUCK; b += 512) {
        u32 pad = rup8(h[b]);                 // identical to k_bhist's contribution
        base[b] = pad ? (u32)atomicAdd(&gcur[b], (int)pad) : 0u;
        h[b] = 0;  // reuse as local cursor
    }
    __syncthreads();
#pragma unroll 4
    for (int i = 0; i < CHUNK / 512; i++) {
        int e = c0 + i * 512 + t;
        if (e < NEDGES) {
            u32 d  = (u32)dst[e];
            u32 bk = d >> 10;
            u32 off = atomicAdd(&h[bk], 1u);
            u32 pos = base[bk] + off;
            u32 ap;
            if (isf32) {
                float2 a = ((const float2*)attr)[e];
                ap = (u32)f2b(a.x) | ((u32)f2b(a.y) << 16);
            } else {
                ap = ((const u32*)attr)[e];
            }
            uint2 rec;
            rec.x = ((u32)src[e]) | ((d & 1023u) << 21);
            rec.y = ap;
            perm[pos] = rec;
        }
    }
    __syncthreads();
    // tail padding: dummy records complete this block's exclusive 64B lines
    for (int b = t; b < NBUCK; b += 512) {
        u32 c = h[b];                          // raw count again
        u32 pad = rup8(c);
        uint2 dummy; dummy.x = TRASH << 21; dummy.y = 0;
        for (u32 k = c; k < pad; k++) perm[base[b] + k] = dummy;
    }
}

// ---- layer 1 (edge-centric): gather scalar x, fixed-point LDS accumulate ----

__global__ __launch_bounds__(256) void k_eagg1(
        const int* __restrict__ bstart, const uint2* __restrict__ perm,
        const void* __restrict__ x,
        const void* Wx, const void* bx, const void* We, const void* be,
        const void* Wo, const void* bo, const void* Wxn, const void* bxn,
        uint4* __restrict__ hA, u16* __restrict__ hB,
        const int* __restrict__ flag) {
    __shared__ int acc[1025 * 9];              // row 1024 = trash
    __shared__ float sWx[9], sbx[9], sWe[18], sbe[9], sWo[81], sbo[9], sWxn[81], sbxn[9];
    int isf32 = *flag;
    int t = threadIdx.x;
    if (t < 9)  sWx[t]  = ldw(Wx,  t, isf32);
    if (t < 9)  sbx[t]  = ldw(bx,  t, isf32);
    if (t < 18) sWe[t]  = ldw(We,  t, isf32);
    if (t < 9)  sbe[t]  = ldw(be,  t, isf32);
    if (t < 81) sWo[t]  = ldw(Wo,  t, isf32);
    if (t < 9)  sbo[t]  = ldw(bo,  t, isf32);
    if (t < 81) sWxn[t] = ldw(Wxn, t, isf32);
    if (t < 9)  sbxn[t] = ldw(bxn, t, isf32);
    for (int i = t; i < 1025 * 9; i += 256) acc[i] = 0;
    __syncthreads();

    int b = blockIdx.x;
    int r0 = bstart[b], r1 = bstart[b + 1];
    for (int i = r0 + t; i < r1; i += 256) {
        uint2 rec = perm[i];
        int   l   = (int)(rec.x >> 21);        // 0..1023 real, 1024 dummy
        int   s   = (int)(rec.x & SRCMASK);
        float xs  = isf32 ? ((const float*)x)[s] : b2f((u32)((const u16*)x)[s]);
        float a0  = b2f(rec.y & 0xffffu);
        float a1  = b2f(rec.y >> 16);
        int* ap = &acc[l * 9];
#pragma unroll
        for (int j = 0; j < 9; j++) {
            float e  = fmaf(a0, sWe[2 * j], fmaf(a1, sWe[2 * j + 1], sbe[j]));
            float hh = fmaf(xs, sWx[j], sbx[j]);
            atomicAdd(&ap[j], fx(hh * e));     // native ds_add_u32
        }
    }
    __syncthreads();

    for (int l = t; l < 1024; l += 256) {
        int n = b * 1024 + l;
        if (n >= NNODES) break;
        float av[9];
#pragma unroll
        for (int j = 0; j < 9; j++) av[j] = (float)acc[l * 9 + j] * FXINV;
        float o[9];
#pragma unroll
        for (int k = 0; k < 9; k++) {
            float v = sbo[k];
#pragma unroll
            for (int j = 0; j < 9; j++) v = fmaf(av[j], sWo[k * 9 + j], v);
            o[k] = fmaxf(v, 0.f);
        }
        u16 hv[9];
#pragma unroll
        for (int j = 0; j < 9; j++) {
            float v = sbxn[j];
#pragma unroll
            for (int k = 0; k < 9; k++) v = fmaf(o[k], sWxn[j * 9 + k], v);
            hv[j] = f2b(v);
        }
        uint4 q;
        q.x = (u32)hv[0] | ((u32)hv[1] << 16);
        q.y = (u32)hv[2] | ((u32)hv[3] << 16);
        q.z = (u32)hv[4] | ((u32)hv[5] << 16);
        q.w = (u32)hv[6] | ((u32)hv[7] << 16);
        hA[n] = q;
        hB[n] = hv[8];
    }
}

// ---- layers 2/3 (edge-centric): gather 16B+2B, fixed-point LDS accumulate --

template <int OUTF, bool FUSE_NEXT>
__global__ __launch_bounds__(256) void k_eagg(
        const int* __restrict__ bstart, const uint2* __restrict__ perm,
        const uint4* __restrict__ hA, const u16* __restrict__ hB,
        const void* We, const void* be, const void* Wo, const void* bo,
        const void* Wxn, const void* bxn,
        uint4* __restrict__ oA, u16* __restrict__ oB,
        const int* __restrict__ flag) {
    __shared__ int acc[1025 * 9];              // row 1024 = trash
    __shared__ float sWe[18], sbe[9], sWo[OUTF * 9], sbo[OUTF], sWxn[81], sbxn[9];
    int isf32 = *flag;
    int t = threadIdx.x;
    if (t < 18)       sWe[t] = ldw(We, t, isf32);
    if (t < 9)        sbe[t] = ldw(be, t, isf32);
    if (t < OUTF * 9) sWo[t] = ldw(Wo, t, isf32);
    if (t < OUTF)     sbo[t] = ldw(bo, t, isf32);
    if constexpr (FUSE_NEXT) {
        if (t < 81) sWxn[t] = ldw(Wxn, t, isf32);
        if (t < 9)  sbxn[t] = ldw(bxn, t, isf32);
    }
    for (int i = t; i < 1025 * 9; i += 256) acc[i] = 0;
    __syncthreads();

    int b = blockIdx.x;
    int r0 = bstart[b], r1 = bstart[b + 1];
    for (int i = r0 + t; i < r1; i += 256) {
        uint2 rec = perm[i];
        int   s   = (int)(rec.x & SRCMASK);
        int   l   = (int)(rec.x >> 21);
        float a0  = b2f(rec.y & 0xffffu);
        float a1  = b2f(rec.y >> 16);
        uint4 qa  = hA[s];
        u32   qb  = (u32)hB[s];
        float h[9];
        h[0] = b2f(qa.x & 0xffffu); h[1] = b2f(qa.x >> 16);
        h[2] = b2f(qa.y & 0xffffu); h[3] = b2f(qa.y >> 16);
        h[4] = b2f(qa.z & 0xffffu); h[5] = b2f(qa.z >> 16);
        h[6] = b2f(qa.w & 0xffffu); h[7] = b2f(qa.w >> 16);
        h[8] = b2f(qb);
        int* ap = &acc[l * 9];
#pragma unroll
        for (int j = 0; j < 9; j++) {
            float e = fmaf(a0, sWe[2 * j], fmaf(a1, sWe[2 * j + 1], sbe[j]));
            atomicAdd(&ap[j], fx(h[j] * e));
        }
    }
    __syncthreads();

    for (int l = t; l < 1024; l += 256) {
        int n = b * 1024 + l;
        if (n >= NNODES) break;
        float av[9];
#pragma unroll
        for (int j = 0; j < 9; j++) av[j] = (float)acc[l * 9 + j] * FXINV;
        float o[OUTF];
#pragma unroll
        for (int k = 0; k < OUTF; k++) {
            float v = sbo[k];
#pragma unroll
            for (int j = 0; j < 9; j++) v = fmaf(av[j], sWo[k * 9 + j], v);
            o[k] = fmaxf(v, 0.f);
        }
        if constexpr (FUSE_NEXT) {
            u16 hv[9];
#pragma unroll
            for (int j = 0; j < 9; j++) {
                float v = sbxn[j];
#pragma unroll
                for (int k = 0; k < OUTF; k++) v = fmaf(o[k], sWxn[j * 9 + k], v);
                hv[j] = f2b(v);
            }
            uint4 q;
            q.x = (u32)hv[0] | ((u32)hv[1] << 16);
            q.y = (u32)hv[2] | ((u32)hv[3] << 16);
            q.z = (u32)hv[4] | ((u32)hv[5] << 16);
            q.w = (u32)hv[6] | ((u32)hv[7] << 16);
            oA[n] = q;
            oB[n] = hv[8];
        } else {
            uint2 q;
            q.x = (u32)f2b(o[0]) | ((u32)f2b(o[1]) << 16);
            q.y = (u32)f2b(o[2]) | ((u32)f2b(o[3]) << 16);
            ((uint2*)oA)[n] = q;   // f table: 8B/node
        }
    }
}

// ---------------- head MLP + log_softmax ----------------

__global__ __launch_bounds__(256) void k_head(
        const u16* __restrict__ f,
        const void* W1, const void* b1, const void* W2, const void* b2,
        void* __restrict__ out, const int* __restrict__ flag) {
    __shared__ float sW1[192], sb1[8], sW2[32], sb2[4];
    int isf32 = *flag;
    int t = threadIdx.x;
    if (t < 192) sW1[t] = ldw(W1, t, isf32);
    if (t < 8)   sb1[t] = ldw(b1, t, isf32);
    if (t < 32)  sW2[t] = ldw(W2, t, isf32);
    if (t < 4)   sb2[t] = ldw(b2, t, isf32);
    __syncthreads();

    int tr = blockIdx.x * 256 + t;
    if (tr >= NTRACK) return;

    const uint4* fp = (const uint4*)(f + (size_t)tr * 24);
    uint4 A = fp[0], B = fp[1], C = fp[2];
    u32 w[12] = {A.x, A.y, A.z, A.w, B.x, B.y, B.z, B.w, C.x, C.y, C.z, C.w};
    float in[24];
#pragma unroll
    for (int i = 0; i < 12; i++) {
        in[2 * i]     = b2f(w[i] & 0xffffu);
        in[2 * i + 1] = b2f(w[i] >> 16);
    }

    float z1[8];
#pragma unroll
    for (int o = 0; o < 8; o++) {
        float v = sb1[o];
#pragma unroll
        for (int i = 0; i < 24; i++) v = fmaf(in[i], sW1[o * 24 + i], v);
        z1[o] = fmaxf(v, 0.f);
    }
    float z2[4];
#pragma unroll
    for (int c = 0; c < 4; c++) {
        float v = sb2[c];
#pragma unroll
        for (int o = 0; o < 8; o++) v = fmaf(z1[o], sW2[c * 8 + o], v);
        z2[c] = v;
    }
    float m = fmaxf(fmaxf(z2[0], z2[1]), fmaxf(z2[2], z2[3]));
    float s = 0.f;
#pragma unroll
    for (int c = 0; c < 4; c++) s += expf(z2[c] - m);
    float l = logf(s) + m;

    if (isf32) {
        float4 q; q.x = z2[0] - l; q.y = z2[1] - l; q.z = z2[2] - l; q.w = z2[3] - l;
        ((float4*)((float*)out + (size_t)tr * 4))[0] = q;
    } else {
        uint2 q;
        q.x = (u32)f2b(z2[0] - l) | ((u32)f2b(z2[1] - l) << 16);
        q.y = (u32)f2b(z2[2] - l) | ((u32)f2b(z2[3] - l) << 16);
        ((uint2*)((u16*)out + (size_t)tr * 4))[0] = q;
    }
}

// ---------------- host ----------------

extern "C" void kernel_launch(void* const* d_in, const int* in_sizes, int n_in,
                              void* d_out, int out_size, void* d_ws, size_t ws_size,
                              hipStream_t stream) {
    const void* X    = d_in[0];
    const int* eidx  = (const int*)d_in[1];
    const void* eattr= d_in[2];
    const void *WX1 = d_in[3],  *BX1 = d_in[4];
    const void *WE1 = d_in[5],  *BE1 = d_in[6];
    const void *WO1 = d_in[7],  *BO1 = d_in[8];
    const void *WX2 = d_in[9],  *BX2 = d_in[10];
    const void *WE2 = d_in[11], *BE2 = d_in[12];
    const void *WO2 = d_in[13], *BO2 = d_in[14];
    const void *WX3 = d_in[15], *BX3 = d_in[16];
    const void *WE3 = d_in[17], *BE3 = d_in[18];
    const void *WO3 = d_in[19], *BO3 = d_in[20];
    const void *W1  = d_in[21], *B1  = d_in[22];
    const void *W2  = d_in[23], *B2  = d_in[24];

    const int* src = eidx;
    const int* dst = eidx + NEDGES;

    // workspace layout (~180.1 MB, <= R2's proven 180.4 MB footprint)
    char* w = (char*)d_ws;
    size_t off = 0;
    auto take = [&](size_t bytes) -> void* {
        void* p = w + off;
        off += (bytes + 255) & ~(size_t)255;
        return p;
    };
    int*   flag   = (int*)take(256);
    int*   gh     = (int*)take((size_t)NBUCK * 4);
    int*   bstart = (int*)take((size_t)(NBUCK + 1) * 4);
    int*   gcur   = (int*)take((size_t)NBUCK * 4);
    uint2* perm   = (uint2*)take((size_t)PERMCAP * 8);     // 126.1 MB cap
    uint4* hA2    = (uint4*)take((size_t)NNODES * 16);     // 24 MB
    u16*   hB2    = (u16*)take((size_t)NNODES * 2);        // 3 MB
    uint4* hA3    = (uint4*)take((size_t)NNODES * 16);     // 24 MB
    u16*   hB3    = (u16*)take((size_t)NNODES * 2);        // 3 MB
    u16*   f      = (u16*)hA2;  // layer-3 output (12 MB) reuses hA2 (dead by then)
    (void)ws_size; (void)n_in; (void)in_sizes; (void)out_size;

    const int TB = (NTRACK + 255) / 256;

    hipMemsetAsync(gh, 0, (size_t)NBUCK * 4, stream);

    k_detect <<<1,    64,  0, stream>>>((const u16*)BX1, (const u16*)BE1, (const u16*)BO1,
                                        (const u16*)BX2, (const u16*)BE2, (const u16*)B1, flag);
    k_bhist  <<<PBLK, 512, 0, stream>>>(dst, gh);
    k_bscan  <<<1,    256, 0, stream>>>(gh, bstart, gcur);
    k_part   <<<PBLK, 512, 0, stream>>>(src, dst, eattr, gcur, perm, flag);

    k_eagg1        <<<NBUCK, 256, 0, stream>>>(bstart, perm, X,
                                               WX1, BX1, WE1, BE1, WO1, BO1, WX2, BX2,
                                               hA2, hB2, flag);
    k_eagg<9,true> <<<NBUCK, 256, 0, stream>>>(bstart, perm, hA2, hB2,
                                               WE2, BE2, WO2, BO2, WX3, BX3,
                                               hA3, hB3, flag);
    k_eagg<4,false><<<NBUCK, 256, 0, stream>>>(bstart, perm, hA3, hB3,
                                               WE3, BE3, WO3, BO3, WO3, BO3,
                                               (uint4*)f, (u16*)f, flag);
    k_head         <<<TB,    256, 0, stream>>>(f, W1, B1, W2, B2, d_out, flag);
}

// Round 7
// 1120.744 us; speedup vs baseline: 2.1378x; 1.1903x over previous
//
#include <hip/hip_runtime.h>
#include <hip/hip_bf16.h>

// trackletGNN: 3x edge-conv + MLP head.
// R7: k_part rewritten as chunk-local LDS counting sort + ordered flush.
// R6 post-mortem: 64B-aligned padded runs still showed WRITE=356MB because
// amplification was TEMPORAL (block's 256KB live write footprint x ~60
// blocks/XCD >> 4MB L2 -> partial-line evictions), not alignment. Now each
// 4096-edge block sorts records into LDS (rec 32KB + per-slot gaddr 16KB),
// reserves exact unpadded runs, and flushes in slot order: every line is
// written in one burst. Unpadded perm = exactly 96MB; TRASH row dropped.
// Layer-1 gathers go back to a 3MB bf16 x-table (k_xcast): fits per-XCD L2,
// unlike the 6MB f32 table R6 gathered from (768MB of L3 line traffic).
// Aggs keep fixed-point ds_add_u32 LDS accumulation. Workspace ~150MB.

#define NNODES 1500000
#define NEDGES 12000000
#define NTRACK 250000
#define NBUCK  1465        // ceil(NNODES/1024), 1024-node agg buckets
#define PCHUNK 4096        // edges per k_part block (LDS-sorted)
#define PBLK   2930        // ceil(NEDGES/PCHUNK)
#define HCHUNK 32768       // edges per k_bhist block
#define HBLK   367         // ceil(NEDGES/HCHUNK)
#define SRCMASK 0x1FFFFFu  // 21 bits
#define FXSCALE 16777216.f // 2^24
#define FXINV   (1.f / 16777216.f)

typedef unsigned int   u32;
typedef unsigned short u16;

static __device__ __forceinline__ float b2f(u32 v) {
    union { float f; u32 u; } x; x.u = v << 16; return x.f;
}
static __device__ __forceinline__ u16 f2b(float f) {
    __hip_bfloat16 h = __float2bfloat16(f);
    return *reinterpret_cast<u16*>(&h);
}
static __device__ __forceinline__ float ldw(const void* p, int i, int isf32) {
    return isf32 ? ((const float*)p)[i] : b2f((u32)((const u16*)p)[i]);
}
static __device__ __forceinline__ int fx(float f) {
    return (int)rintf(f * FXSCALE);
}

// ---------------- dtype probe ----------------

__global__ void k_detect(const u16* a, const u16* b, const u16* c,
                         const u16* d, const u16* e, const u16* f,
                         int* flag) {
    if (blockIdx.x == 0 && threadIdx.x == 0) {
        int isf32 = 0;
        const u16* ps[6] = {a, b, c, d, e, f};
        const int  ns[6] = {9, 9, 9, 9, 9, 8};
        for (int k = 0; k < 6; k++)
            for (int i = 0; i < ns[k]; i++) {
                float v = b2f((u32)ps[k][i]);
                if (!(fabsf(v) < 1.0e3f)) isf32 = 1;   // catches NaN/Inf too
            }
        *flag = isf32;
    }
}

// ------------- x -> bf16 table (3 MB, fits per-XCD L2 for layer 1) -------

__global__ __launch_bounds__(256) void k_xcast(const void* __restrict__ x,
                                               u16* __restrict__ xb,
                                               const int* __restrict__ flag) {
    int isf32 = *flag;
    int n = blockIdx.x * 256 + threadIdx.x;
    if (n < NNODES)
        xb[n] = isf32 ? f2b(((const float*)x)[n]) : ((const u16*)x)[n];
}

// ---------------- bucket histogram + scan (exact, unpadded) --------------

__global__ __launch_bounds__(512) void k_bhist(const int* __restrict__ dst,
                                               int* __restrict__ gh) {
    __shared__ u32 h[NBUCK];
    int t = threadIdx.x;
    for (int b = t; b < NBUCK; b += 512) h[b] = 0;
    __syncthreads();
    int c0 = blockIdx.x * HCHUNK;
#pragma unroll 4
    for (int i = 0; i < HCHUNK / 512; i++) {
        int e = c0 + i * 512 + t;
        if (e < NEDGES) atomicAdd(&h[((u32)dst[e]) >> 10], 1u);
    }
    __syncthreads();
    for (int b = t; b < NBUCK; b += 512) {
        u32 c = h[b];
        if (c) atomicAdd((u32*)&gh[b], c);
    }
}

__global__ __launch_bounds__(256) void k_bscan(const int* __restrict__ gh,
                                               int* __restrict__ bstart,
                                               int* __restrict__ gcur) {
    __shared__ u32 sd[256];
    __shared__ u32 carry;
    int t = threadIdx.x;
    if (t == 0) carry = 0;
    __syncthreads();
    for (int c0 = 0; c0 < NBUCK; c0 += 256) {
        int b = c0 + t;
        u32 v = (b < NBUCK) ? (u32)gh[b] : 0;
        sd[t] = v; __syncthreads();
        for (int o = 1; o < 256; o <<= 1) {
            u32 a = (t >= o) ? sd[t - o] : 0;
            __syncthreads();
            sd[t] += a;
            __syncthreads();
        }
        u32 excl = carry + sd[t] - v;
        if (b < NBUCK) { bstart[b] = (int)excl; gcur[b] = (int)excl; }
        __syncthreads();
        if (t == 255) carry += sd[255];
        __syncthreads();
    }
    if (t == 0) bstart[NBUCK] = NEDGES;
}

// ---- partition: chunk-local LDS counting sort + ordered coalesced flush ----

__global__ __launch_bounds__(512) void k_part(const int* __restrict__ src,
                                              const int* __restrict__ dst,
                                              const void* __restrict__ attr,
                                              int* __restrict__ gcur,
                                              uint2* __restrict__ perm,
                                              const int* __restrict__ flag) {
    __shared__ int   cur[NBUCK];    // hist -> local exclusive start -> cursor
    __shared__ int   gbA[NBUCK];    // global run base minus local start
    __shared__ uint2 rec[PCHUNK];   // bucket-grouped records
    __shared__ u32   gad[PCHUNK];   // per-slot global address
    __shared__ u32   sd[512];
    __shared__ u32   carryS;
    int isf32 = *flag;
    int t = threadIdx.x;
    int c0 = blockIdx.x * PCHUNK;
    int chunkN = NEDGES - c0; if (chunkN > PCHUNK) chunkN = PCHUNK;

    for (int b = t; b < NBUCK; b += 512) cur[b] = 0;
    if (t == 0) carryS = 0;
    __syncthreads();

    // phase 1: histogram; keep src/dst in registers
    int ds_[8], sr_[8];
#pragma unroll
    for (int k = 0; k < 8; k++) {
        int e = c0 + k * 512 + t;
        if (e < NEDGES) {
            ds_[k] = dst[e];
            sr_[k] = src[e];
            atomicAdd((u32*)&cur[((u32)ds_[k]) >> 10], 1u);
        } else { ds_[k] = -1; sr_[k] = 0; }
    }
    __syncthreads();

    // phase 2: exclusive scan of cur + global run reservation
    for (int b0 = 0; b0 < NBUCK; b0 += 512) {
        int b = b0 + t;
        u32 v = (b < NBUCK) ? (u32)cur[b] : 0;
        sd[t] = v; __syncthreads();
        for (int o = 1; o < 512; o <<= 1) {
            u32 a = (t >= o) ? sd[t - o] : 0;
            __syncthreads();
            sd[t] += a;
            __syncthreads();
        }
        u32 excl = carryS + sd[t] - v;
        if (b < NBUCK) {
            cur[b] = (int)excl;
            if (v) gbA[b] = atomicAdd(&gcur[b], (int)v) - (int)excl;
        }
        __syncthreads();
        if (t == 511) carryS += sd[511];
        __syncthreads();
    }

    // phase 3: scatter records into LDS, record global addresses
#pragma unroll
    for (int k = 0; k < 8; k++) {
        int e = c0 + k * 512 + t;
        if (e < NEDGES) {
            u32 d  = (u32)ds_[k];
            u32 fb = d >> 10;
            u32 ap;
            if (isf32) {
                float2 a = ((const float2*)attr)[e];
                ap = (u32)f2b(a.x) | ((u32)f2b(a.y) << 16);
            } else {
                ap = ((const u32*)attr)[e];
            }
            int slot = atomicAdd(&cur[fb], 1);
            uint2 r; r.x = ((u32)sr_[k]) | ((d & 1023u) << 21); r.y = ap;
            rec[slot] = r;
            gad[slot] = (u32)(gbA[fb] + slot);
        }
    }
    __syncthreads();

    // phase 4: ordered flush -- slot-consecutive => line-burst writes
#pragma unroll
    for (int j = 0; j < 8; j++) {
        int s = j * 512 + t;
        if (s < chunkN) perm[gad[s]] = rec[s];
    }
}

// ---- layer 1 (edge-centric): gather bf16 x (L2-resident), fx LDS acc ----

__global__ __launch_bounds__(256) void k_eagg1(
        const int* __restrict__ bstart, const uint2* __restrict__ perm,
        const u16* __restrict__ xb,
        const void* Wx, const void* bx, const void* We, const void* be,
        const void* Wo, const void* bo, const void* Wxn, const void* bxn,
        uint4* __restrict__ hA, u16* __restrict__ hB,
        const int* __restrict__ flag) {
    __shared__ int acc[1024 * 9];
    __shared__ float sWx[9], sbx[9], sWe[18], sbe[9], sWo[81], sbo[9], sWxn[81], sbxn[9];
    int isf32 = *flag;
    int t = threadIdx.x;
    if (t < 9)  sWx[t]  = ldw(Wx,  t, isf32);
    if (t < 9)  sbx[t]  = ldw(bx,  t, isf32);
    if (t < 18) sWe[t]  = ldw(We,  t, isf32);
    if (t < 9)  sbe[t]  = ldw(be,  t, isf32);
    if (t < 81) sWo[t]  = ldw(Wo,  t, isf32);
    if (t < 9)  sbo[t]  = ldw(bo,  t, isf32);
    if (t < 81) sWxn[t] = ldw(Wxn, t, isf32);
    if (t < 9)  sbxn[t] = ldw(bxn, t, isf32);
    for (int i = t; i < 1024 * 9; i += 256) acc[i] = 0;
    __syncthreads();

    int b = blockIdx.x;
    int r0 = bstart[b], r1 = bstart[b + 1];
    for (int i = r0 + t; i < r1; i += 256) {
        uint2 rec = perm[i];
        int   l   = (int)((rec.x >> 21) & 1023u);
        float xs  = b2f((u32)xb[rec.x & SRCMASK]);
        float a0  = b2f(rec.y & 0xffffu);
        float a1  = b2f(rec.y >> 16);
        int* ap = &acc[l * 9];
#pragma unroll
        for (int j = 0; j < 9; j++) {
            float e  = fmaf(a0, sWe[2 * j], fmaf(a1, sWe[2 * j + 1], sbe[j]));
            float hh = fmaf(xs, sWx[j], sbx[j]);
            atomicAdd(&ap[j], fx(hh * e));     // native ds_add_u32
        }
    }
    __syncthreads();

    for (int l = t; l < 1024; l += 256) {
        int n = b * 1024 + l;
        if (n >= NNODES) break;
        float av[9];
#pragma unroll
        for (int j = 0; j < 9; j++) av[j] = (float)acc[l * 9 + j] * FXINV;
        float o[9];
#pragma unroll
        for (int k = 0; k < 9; k++) {
            float v = sbo[k];
#pragma unroll
            for (int j = 0; j < 9; j++) v = fmaf(av[j], sWo[k * 9 + j], v);
            o[k] = fmaxf(v, 0.f);
        }
        u16 hv[9];
#pragma unroll
        for (int j = 0; j < 9; j++) {
            float v = sbxn[j];
#pragma unroll
            for (int k = 0; k < 9; k++) v = fmaf(o[k], sWxn[j * 9 + k], v);
            hv[j] = f2b(v);
        }
        uint4 q;
        q.x = (u32)hv[0] | ((u32)hv[1] << 16);
        q.y = (u32)hv[2] | ((u32)hv[3] << 16);
        q.z = (u32)hv[4] | ((u32)hv[5] << 16);
        q.w = (u32)hv[6] | ((u32)hv[7] << 16);
        hA[n] = q;
        hB[n] = hv[8];
    }
}

// ---- layers 2/3 (edge-centric): gather 16B+2B, fixed-point LDS acc ----

template <int OUTF, bool FUSE_NEXT>
__global__ __launch_bounds__(256) void k_eagg(
        const int* __restrict__ bstart, const uint2* __restrict__ perm,
        const uint4* __restrict__ hA, const u16* __restrict__ hB,
        const void* We, const void* be, const void* Wo, const void* bo,
        const void* Wxn, const void* bxn,
        uint4* __restrict__ oA, u16* __restrict__ oB,
        const int* __restrict__ flag) {
    __shared__ int acc[1024 * 9];
    __shared__ float sWe[18], sbe[9], sWo[OUTF * 9], sbo[OUTF], sWxn[81], sbxn[9];
    int isf32 = *flag;
    int t = threadIdx.x;
    if (t < 18)       sWe[t] = ldw(We, t, isf32);
    if (t < 9)        sbe[t] = ldw(be, t, isf32);
    if (t < OUTF * 9) sWo[t] = ldw(Wo, t, isf32);
    if (t < OUTF)     sbo[t] = ldw(bo, t, isf32);
    if constexpr (FUSE_NEXT) {
        if (t < 81) sWxn[t] = ldw(Wxn, t, isf32);
        if (t < 9)  sbxn[t] = ldw(bxn, t, isf32);
    }
    for (int i = t; i < 1024 * 9; i += 256) acc[i] = 0;
    __syncthreads();

    int b = blockIdx.x;
    int r0 = bstart[b], r1 = bstart[b + 1];
    for (int i = r0 + t; i < r1; i += 256) {
        uint2 rec = perm[i];
        int   s   = (int)(rec.x & SRCMASK);
        int   l   = (int)((rec.x >> 21) & 1023u);
        float a0  = b2f(rec.y & 0xffffu);
        float a1  = b2f(rec.y >> 16);
        uint4 qa  = hA[s];
        u32   qb  = (u32)hB[s];
        float h[9];
        h[0] = b2f(qa.x & 0xffffu); h[1] = b2f(qa.x >> 16);
        h[2] = b2f(qa.y & 0xffffu); h[3] = b2f(qa.y >> 16);
        h[4] = b2f(qa.z & 0xffffu); h[5] = b2f(qa.z >> 16);
        h[6] = b2f(qa.w & 0xffffu); h[7] = b2f(qa.w >> 16);
        h[8] = b2f(qb);
        int* ap = &acc[l * 9];
#pragma unroll
        for (int j = 0; j < 9; j++) {
            float e = fmaf(a0, sWe[2 * j], fmaf(a1, sWe[2 * j + 1], sbe[j]));
            atomicAdd(&ap[j], fx(h[j] * e));
        }
    }
    __syncthreads();

    for (int l = t; l < 1024; l += 256) {
        int n = b * 1024 + l;
        if (n >= NNODES) break;
        float av[9];
#pragma unroll
        for (int j = 0; j < 9; j++) av[j] = (float)acc[l * 9 + j] * FXINV;
        float o[OUTF];
#pragma unroll
        for (int k = 0; k < OUTF; k++) {
            float v = sbo[k];
#pragma unroll
            for (int j = 0; j < 9; j++) v = fmaf(av[j], sWo[k * 9 + j], v);
            o[k] = fmaxf(v, 0.f);
        }
        if constexpr (FUSE_NEXT) {
            u16 hv[9];
#pragma unroll
            for (int j = 0; j < 9; j++) {
                float v = sbxn[j];
#pragma unroll
                for (int k = 0; k < OUTF; k++) v = fmaf(o[k], sWxn[j * 9 + k], v);
                hv[j] = f2b(v);
            }
            uint4 q;
            q.x = (u32)hv[0] | ((u32)hv[1] << 16);
            q.y = (u32)hv[2] | ((u32)hv[3] << 16);
            q.z = (u32)hv[4] | ((u32)hv[5] << 16);
            q.w = (u32)hv[6] | ((u32)hv[7] << 16);
            oA[n] = q;
            oB[n] = hv[8];
        } else {
            uint2 q;
            q.x = (u32)f2b(o[0]) | ((u32)f2b(o[1]) << 16);
            q.y = (u32)f2b(o[2]) | ((u32)f2b(o[3]) << 16);
            ((uint2*)oA)[n] = q;   // f table: 8B/node
        }
    }
}

// ---------------- head MLP + log_softmax ----------------

__global__ __launch_bounds__(256) void k_head(
        const u16* __restrict__ f,
        const void* W1, const void* b1, const void* W2, const void* b2,
        void* __restrict__ out, const int* __restrict__ flag) {
    __shared__ float sW1[192], sb1[8], sW2[32], sb2[4];
    int isf32 = *flag;
    int t = threadIdx.x;
    if (t < 192) sW1[t] = ldw(W1, t, isf32);
    if (t < 8)   sb1[t] = ldw(b1, t, isf32);
    if (t < 32)  sW2[t] = ldw(W2, t, isf32);
    if (t < 4)   sb2[t] = ldw(b2, t, isf32);
    __syncthreads();

    int tr = blockIdx.x * 256 + t;
    if (tr >= NTRACK) return;

    const uint4* fp = (const uint4*)(f + (size_t)tr * 24);
    uint4 A = fp[0], B = fp[1], C = fp[2];
    u32 w[12] = {A.x, A.y, A.z, A.w, B.x, B.y, B.z, B.w, C.x, C.y, C.z, C.w};
    float in[24];
#pragma unroll
    for (int i = 0; i < 12; i++) {
        in[2 * i]     = b2f(w[i] & 0xffffu);
        in[2 * i + 1] = b2f(w[i] >> 16);
    }

    float z1[8];
#pragma unroll
    for (int o = 0; o < 8; o++) {
        float v = sb1[o];
#pragma unroll
        for (int i = 0; i < 24; i++) v = fmaf(in[i], sW1[o * 24 + i], v);
        z1[o] = fmaxf(v, 0.f);
    }
    float z2[4];
#pragma unroll
    for (int c = 0; c < 4; c++) {
        float v = sb2[c];
#pragma unroll
        for (int o = 0; o < 8; o++) v = fmaf(z1[o], sW2[c * 8 + o], v);
        z2[c] = v;
    }
    float m = fmaxf(fmaxf(z2[0], z2[1]), fmaxf(z2[2], z2[3]));
    float s = 0.f;
#pragma unroll
    for (int c = 0; c < 4; c++) s += expf(z2[c] - m);
    float l = logf(s) + m;

    if (isf32) {
        float4 q; q.x = z2[0] - l; q.y = z2[1] - l; q.z = z2[2] - l; q.w = z2[3] - l;
        ((float4*)((float*)out + (size_t)tr * 4))[0] = q;
    } else {
        uint2 q;
        q.x = (u32)f2b(z2[0] - l) | ((u32)f2b(z2[1] - l) << 16);
        q.y = (u32)f2b(z2[2] - l) | ((u32)f2b(z2[3] - l) << 16);
        ((uint2*)((u16*)out + (size_t)tr * 4))[0] = q;
    }
}

// ---------------- host ----------------

extern "C" void kernel_launch(void* const* d_in, const int* in_sizes, int n_in,
                              void* d_out, int out_size, void* d_ws, size_t ws_size,
                              hipStream_t stream) {
    const void* X    = d_in[0];
    const int* eidx  = (const int*)d_in[1];
    const void* eattr= d_in[2];
    const void *WX1 = d_in[3],  *BX1 = d_in[4];
    const void *WE1 = d_in[5],  *BE1 = d_in[6];
    const void *WO1 = d_in[7],  *BO1 = d_in[8];
    const void *WX2 = d_in[9],  *BX2 = d_in[10];
    const void *WE2 = d_in[11], *BE2 = d_in[12];
    const void *WO2 = d_in[13], *BO2 = d_in[14];
    const void *WX3 = d_in[15], *BX3 = d_in[16];
    const void *WE3 = d_in[17], *BE3 = d_in[18];
    const void *WO3 = d_in[19], *BO3 = d_in[20];
    const void *W1  = d_in[21], *B1  = d_in[22];
    const void *W2  = d_in[23], *B2  = d_in[24];

    const int* src = eidx;
    const int* dst = eidx + NEDGES;

    // workspace layout (~150 MB)
    char* w = (char*)d_ws;
    size_t off = 0;
    auto take = [&](size_t bytes) -> void* {
        void* p = w + off;
        off += (bytes + 255) & ~(size_t)255;
        return p;
    };
    int*   flag   = (int*)take(256);
    int*   gh     = (int*)take((size_t)NBUCK * 4);
    int*   bstart = (int*)take((size_t)(NBUCK + 1) * 4);
    int*   gcur   = (int*)take((size_t)NBUCK * 4);
    u16*   xb     = (u16*)take((size_t)NNODES * 2);        // 3 MB bf16 x
    uint2* perm   = (uint2*)take((size_t)NEDGES * 8);      // 96 MB exact
    uint4* hA2    = (uint4*)take((size_t)NNODES * 16);     // 24 MB
    u16*   hB2    = (u16*)take((size_t)NNODES * 2);        // 3 MB
    uint4* hA3    = (uint4*)take((size_t)NNODES * 16);     // 24 MB
    u16*   hB3    = (u16*)take((size_t)NNODES * 2);        // 3 MB
    u16*   f      = (u16*)hA2;  // layer-3 output (12 MB) reuses hA2 (dead by then)
    (void)ws_size; (void)n_in; (void)in_sizes; (void)out_size;

    const int NB = (NNODES + 255) / 256;
    const int TB = (NTRACK + 255) / 256;

    hipMemsetAsync(gh, 0, (size_t)NBUCK * 4, stream);

    k_detect <<<1,    64,  0, stream>>>((const u16*)BX1, (const u16*)BE1, (const u16*)BO1,
                                        (const u16*)BX2, (const u16*)BE2, (const u16*)B1, flag);
    k_xcast  <<<NB,   256, 0, stream>>>(X, xb, flag);
    k_bhist  <<<HBLK, 512, 0, stream>>>(dst, gh);
    k_bscan  <<<1,    256, 0, stream>>>(gh, bstart, gcur);
    k_part   <<<PBLK, 512, 0, stream>>>(src, dst, eattr, gcur, perm, flag);

    k_eagg1        <<<NBUCK, 256, 0, stream>>>(bstart, perm, xb,
                                               WX1, BX1, WE1, BE1, WO1, BO1, WX2, BX2,
                                               hA2, hB2, flag);
    k_eagg<9,true> <<<NBUCK, 256, 0, stream>>>(bstart, perm, hA2, hB2,
                                               WE2, BE2, WO2, BO2, WX3, BX3,
                                               hA3, hB3, flag);
    k_eagg<4,false><<<NBUCK, 256, 0, stream>>>(bstart, perm, hA3, hB3,
                                               WE3, BE3, WO3, BO3, WO3, BO3,
                                               (uint4*)f, (u16*)f, flag);
    k_head         <<<TB,    256, 0, stream>>>(f, W1, B1, W2, B2, d_out, flag);
}